// Round 1
// baseline (2672.646 us; speedup 1.0000x reference)
//
#include <hip/hip_runtime.h>
#include <math.h>

#define N_EDGE 262144
#define N_TRI  1048576
#define DIM    128
#define NRBF   6
#define ADIM   49
#define NBIL   8
#define TE     32     // edges per block in edge_main
#define BT     256    // threads per block

__device__ __forceinline__ float silu_f(float x) { return x / (1.0f + __expf(-x)); }

// ---------------------------------------------------------------------------
// repack final_w [i][j][l] -> fwp [j][l][i]  (512 KB, coalesced writes)
// ---------------------------------------------------------------------------
__global__ void repack_fw_k(const float* __restrict__ fw, float* __restrict__ fwp)
{
    int idx = blockIdx.x * 256 + threadIdx.x;      // 131072 total
    int i = idx & 127;
    int l = (idx >> 7) & 127;
    int j = idx >> 14;
    fwp[idx] = fw[(i * NBIL + j) * DIM + l];
}

// ---------------------------------------------------------------------------
// triplet stage: t_a = a_sbf @ a_sbf_w  [W,8]; atomic segment-sum into ta_sum
// ---------------------------------------------------------------------------
__global__ __launch_bounds__(256) void triplet_ta_k(
    const float* __restrict__ a_sbf, const float* __restrict__ a_sbf_w,
    const int* __restrict__ kj_idx, float* __restrict__ ta_sum)
{
    __shared__ __align__(16) float sA[256 * ADIM];   // 49 KB
    __shared__ float sWa[ADIM * NBIL];               // 392 floats
    const int tid = threadIdx.x;
    const size_t w0 = (size_t)blockIdx.x * 256;

    {
        const float4* src = (const float4*)(a_sbf + w0 * ADIM);
        float4* dst = (float4*)sA;
        const int n4 = (256 * ADIM) / 4;             // 3136
        for (int i = tid; i < n4; i += 256) dst[i] = src[i];
    }
    for (int i = tid; i < ADIM * NBIL; i += 256) sWa[i] = a_sbf_w[i];
    __syncthreads();

    float ta[NBIL];
    #pragma unroll
    for (int j = 0; j < NBIL; ++j) ta[j] = 0.0f;
    const float* row = sA + tid * ADIM;
    #pragma unroll
    for (int k = 0; k < ADIM; ++k) {
        float v = row[k];
        #pragma unroll
        for (int j = 0; j < NBIL; ++j) ta[j] = fmaf(v, sWa[k * NBIL + j], ta[j]);
    }
    const int e = kj_idx[w0 + tid];
    float* dst = ta_sum + (size_t)e * NBIL;
    #pragma unroll
    for (int j = 0; j < NBIL; ++j) atomicAdd(dst + j, ta[j]);
}

// ---------------------------------------------------------------------------
// fp32 tile GEMM: acc[4][4] = bias + in[32][128] @ W[128][128] for this
// thread's (4 edges x 4 cols). W streamed through LDS in 16-row chunks.
// ---------------------------------------------------------------------------
__device__ __forceinline__ void gemm_tile(
    const float* __restrict__ in, const float* __restrict__ W,
    const float* __restrict__ bias, float acc[4][4], float* sW, int tid)
{
    const int n4 = tid & 31;
    const int eg = tid >> 5;
    float4 b = *(const float4*)(bias + n4 * 4);
    #pragma unroll
    for (int e = 0; e < 4; ++e) { acc[e][0]=b.x; acc[e][1]=b.y; acc[e][2]=b.z; acc[e][3]=b.w; }

    for (int kc = 0; kc < DIM; kc += 16) {
        __syncthreads();                             // protect sW (prev users done)
        {
            const float4* ws = (const float4*)(W + kc * DIM);
            float4* wd = (float4*)sW;
            wd[tid]       = ws[tid];
            wd[tid + 256] = ws[tid + 256];
        }
        __syncthreads();
        #pragma unroll
        for (int kk = 0; kk < 16; kk += 4) {
            float4 xv[4];
            #pragma unroll
            for (int e = 0; e < 4; ++e)
                xv[e] = *(const float4*)(in + (eg * 4 + e) * DIM + kc + kk);
            #pragma unroll
            for (int q = 0; q < 4; ++q) {
                float4 w = *(const float4*)(sW + (kk + q) * DIM + n4 * 4);
                #pragma unroll
                for (int e = 0; e < 4; ++e) {
                    float xs = (q == 0) ? xv[e].x : (q == 1) ? xv[e].y
                             : (q == 2) ? xv[e].z : xv[e].w;
                    acc[e][0] = fmaf(xs, w.x, acc[e][0]);
                    acc[e][1] = fmaf(xs, w.y, acc[e][1]);
                    acc[e][2] = fmaf(xs, w.z, acc[e][2]);
                    acc[e][3] = fmaf(xs, w.w, acc[e][3]);
                }
            }
        }
    }
}

// ---------------------------------------------------------------------------
// fused edge kernel: whole per-edge pipeline in LDS, one global write
// ---------------------------------------------------------------------------
__global__ __launch_bounds__(256) void edge_main_k(
    const float* __restrict__ m_ji, const float* __restrict__ e_rbf,
    const float* __restrict__ ta_sum, const float* __restrict__ fwp,
    const float* __restrict__ nbr_m_w, const float* __restrict__ nbr_m_b,
    const float* __restrict__ e_rbf_w,
    const float* __restrict__ m_ji_w, const float* __restrict__ m_ji_b,
    const float* __restrict__ post_w, const float* __restrict__ post_b,
    const float* __restrict__ res_w, const float* __restrict__ res_b,
    float* __restrict__ out)
{
    __shared__ __align__(16) float sX[TE * DIM];     // m_ji tile, then x
    __shared__ __align__(16) float sB[TE * DIM];     // m_and_e, then stage temps
    __shared__ __align__(16) float sT[TE * DIM];     // transf
    __shared__ __align__(16) float sW[16 * DIM];     // weight chunk
    __shared__ __align__(16) float sTA[TE * NBIL];
    __shared__ __align__(16) float sE[TE * NRBF];

    const int tid = threadIdx.x;
    const int n4 = tid & 31;
    const int eg = tid >> 5;
    const size_t e0 = (size_t)blockIdx.x * TE;

    {
        const float4* src = (const float4*)(m_ji + e0 * DIM);
        float4* dst = (float4*)sX;
        #pragma unroll
        for (int i = 0; i < 4; ++i) dst[tid + i * 256] = src[tid + i * 256];
    }
    sTA[tid] = ta_sum[e0 * NBIL + tid];              // TE*8 == 256
    if (tid < TE * NRBF) sE[tid] = e_rbf[e0 * NRBF + tid];

    float acc[4][4];

    // stage 1: m_and_e = silu(mji @ nbr_m_w + b) * (e_rbf @ e_rbf_w) -> sB
    gemm_tile(sX, nbr_m_w, nbr_m_b, acc, sW, tid);
    {
        float4 wr[NRBF];
        #pragma unroll
        for (int r = 0; r < NRBF; ++r) wr[r] = *(const float4*)(e_rbf_w + r * DIM + n4 * 4);
        __syncthreads();
        #pragma unroll
        for (int e = 0; e < 4; ++e) {
            const int ee = eg * 4 + e;
            float te0 = 0.f, te1 = 0.f, te2 = 0.f, te3 = 0.f;
            #pragma unroll
            for (int r = 0; r < NRBF; ++r) {
                float er = sE[ee * NRBF + r];
                te0 = fmaf(er, wr[r].x, te0);
                te1 = fmaf(er, wr[r].y, te1);
                te2 = fmaf(er, wr[r].z, te2);
                te3 = fmaf(er, wr[r].w, te3);
            }
            float* p = sB + ee * DIM + n4 * 4;
            p[0] = silu_f(acc[e][0]) * te0;
            p[1] = silu_f(acc[e][1]) * te1;
            p[2] = silu_f(acc[e][2]) * te2;
            p[3] = silu_f(acc[e][3]) * te3;
        }
    }

    // stage 2: transf = silu(mji @ m_ji_w + b) -> sT
    gemm_tile(sX, m_ji_w, m_ji_b, acc, sW, tid);
    __syncthreads();
    #pragma unroll
    for (int e = 0; e < 4; ++e) {
        const int ee = eg * 4 + e;
        float* p = sT + ee * DIM + n4 * 4;
        p[0] = silu_f(acc[e][0]); p[1] = silu_f(acc[e][1]);
        p[2] = silu_f(acc[e][2]); p[3] = silu_f(acc[e][3]);
    }

    // stage 3: bilinear  directed[e,i] = sum_j ta[e,j] * sum_l me[e,l]*fw[i,j,l]
    #pragma unroll
    for (int e = 0; e < 4; ++e) { acc[e][0]=0.f; acc[e][1]=0.f; acc[e][2]=0.f; acc[e][3]=0.f; }
    for (int j = 0; j < NBIL; ++j) {
        float taj[4];
        #pragma unroll
        for (int e = 0; e < 4; ++e) taj[e] = sTA[(eg * 4 + e) * NBIL + j];
        for (int lc = 0; lc < DIM; lc += 16) {
            __syncthreads();
            {
                const float4* ws = (const float4*)(fwp + (size_t)(j * DIM + lc) * DIM);
                float4* wd = (float4*)sW;
                wd[tid]       = ws[tid];
                wd[tid + 256] = ws[tid + 256];
            }
            __syncthreads();
            #pragma unroll
            for (int l4 = 0; l4 < 16; l4 += 4) {
                float4 me[4];
                #pragma unroll
                for (int e = 0; e < 4; ++e)
                    me[e] = *(const float4*)(sB + (eg * 4 + e) * DIM + lc + l4);
                #pragma unroll
                for (int q = 0; q < 4; ++q) {
                    float4 w = *(const float4*)(sW + (l4 + q) * DIM + n4 * 4);
                    #pragma unroll
                    for (int e = 0; e < 4; ++e) {
                        float ms = (q == 0) ? me[e].x : (q == 1) ? me[e].y
                                 : (q == 2) ? me[e].z : me[e].w;
                        float c = taj[e] * ms;
                        acc[e][0] = fmaf(c, w.x, acc[e][0]);
                        acc[e][1] = fmaf(c, w.y, acc[e][1]);
                        acc[e][2] = fmaf(c, w.z, acc[e][2]);
                        acc[e][3] = fmaf(c, w.w, acc[e][3]);
                    }
                }
            }
        }
    }
    __syncthreads();
    #pragma unroll
    for (int e = 0; e < 4; ++e) {                    // x = directed + transf -> sX
        const int ee = eg * 4 + e;
        float* p = sX + ee * DIM + n4 * 4;
        const float* t = sT + ee * DIM + n4 * 4;
        p[0] = acc[e][0] + t[0]; p[1] = acc[e][1] + t[1];
        p[2] = acc[e][2] + t[2]; p[3] = acc[e][3] + t[3];
    }

    // residual block: x = silu(silu(x@w0+b0)@w1+b1) + x
    auto residual = [&](const float* w0, const float* b0,
                        const float* w1, const float* b1) {
        gemm_tile(sX, w0, b0, acc, sW, tid);
        __syncthreads();
        #pragma unroll
        for (int e = 0; e < 4; ++e) {
            const int ee = eg * 4 + e;
            float* p = sB + ee * DIM + n4 * 4;
            p[0] = silu_f(acc[e][0]); p[1] = silu_f(acc[e][1]);
            p[2] = silu_f(acc[e][2]); p[3] = silu_f(acc[e][3]);
        }
        gemm_tile(sB, w1, b1, acc, sW, tid);
        __syncthreads();
        #pragma unroll
        for (int e = 0; e < 4; ++e) {
            const int ee = eg * 4 + e;
            float* p = sX + ee * DIM + n4 * 4;
            p[0] += silu_f(acc[e][0]); p[1] += silu_f(acc[e][1]);
            p[2] += silu_f(acc[e][2]); p[3] += silu_f(acc[e][3]);
        }
    };

    residual(res_w + 0 * 16384, res_b + 0 * 128, res_w + 1 * 16384, res_b + 1 * 128);

    // post: x = silu(x@post_w+pb) + transf
    gemm_tile(sX, post_w, post_b, acc, sW, tid);
    __syncthreads();                                 // all reads of sX done
    #pragma unroll
    for (int e = 0; e < 4; ++e) {
        const int ee = eg * 4 + e;
        float* p = sX + ee * DIM + n4 * 4;
        const float* t = sT + ee * DIM + n4 * 4;
        p[0] = silu_f(acc[e][0]) + t[0]; p[1] = silu_f(acc[e][1]) + t[1];
        p[2] = silu_f(acc[e][2]) + t[2]; p[3] = silu_f(acc[e][3]) + t[3];
    }

    residual(res_w + 2 * 16384, res_b + 2 * 128, res_w + 3 * 16384, res_b + 3 * 128);

    // res2 with fused final store
    gemm_tile(sX, res_w + 4 * 16384, res_b + 4 * 128, acc, sW, tid);
    __syncthreads();
    #pragma unroll
    for (int e = 0; e < 4; ++e) {
        const int ee = eg * 4 + e;
        float* p = sB + ee * DIM + n4 * 4;
        p[0] = silu_f(acc[e][0]); p[1] = silu_f(acc[e][1]);
        p[2] = silu_f(acc[e][2]); p[3] = silu_f(acc[e][3]);
    }
    gemm_tile(sB, res_w + 5 * 16384, res_b + 5 * 128, acc, sW, tid);
    #pragma unroll
    for (int e = 0; e < 4; ++e) {
        const int ee = eg * 4 + e;
        const float* p = sX + ee * DIM + n4 * 4;     // own elements, written by this thread
        float4 o;
        o.x = silu_f(acc[e][0]) + p[0];
        o.y = silu_f(acc[e][1]) + p[1];
        o.z = silu_f(acc[e][2]) + p[2];
        o.w = silu_f(acc[e][3]) + p[3];
        *(float4*)(out + (e0 + ee) * DIM + n4 * 4) = o;
    }
}

// ---------------------------------------------------------------------------
extern "C" void kernel_launch(void* const* d_in, const int* in_sizes, int n_in,
                              void* d_out, int out_size, void* d_ws, size_t ws_size,
                              hipStream_t stream)
{
    (void)in_sizes; (void)n_in; (void)out_size; (void)ws_size;
    const float* m_ji    = (const float*)d_in[0];
    const float* e_rbf   = (const float*)d_in[1];
    const float* a_sbf   = (const float*)d_in[2];
    const int*   kj_idx  = (const int*)d_in[5];
    const float* nbr_m_w = (const float*)d_in[6];
    const float* nbr_m_b = (const float*)d_in[7];
    const float* e_rbf_w = (const float*)d_in[8];
    const float* a_sbf_w = (const float*)d_in[9];
    const float* final_w = (const float*)d_in[10];
    const float* m_ji_w  = (const float*)d_in[11];
    const float* m_ji_b  = (const float*)d_in[12];
    const float* post_w  = (const float*)d_in[13];
    const float* post_b  = (const float*)d_in[14];
    const float* res_w   = (const float*)d_in[15];
    const float* res_b   = (const float*)d_in[16];
    float* out = (float*)d_out;

    float* ta  = (float*)d_ws;                       // [E, 8]
    float* fwp = ta + (size_t)N_EDGE * NBIL;         // [8, 128, 128]

    hipMemsetAsync(ta, 0, (size_t)N_EDGE * NBIL * sizeof(float), stream);
    repack_fw_k<<<512, 256, 0, stream>>>(final_w, fwp);
    triplet_ta_k<<<N_TRI / 256, 256, 0, stream>>>(a_sbf, a_sbf_w, kj_idx, ta);
    edge_main_k<<<N_EDGE / TE, 256, 0, stream>>>(m_ji, e_rbf, ta, fwp,
        nbr_m_w, nbr_m_b, e_rbf_w, m_ji_w, m_ji_b, post_w, post_b,
        res_w, res_b, out);
}

// Round 2
// 1003.384 us; speedup vs baseline: 2.6636x; 2.6636x over previous
//
#include <hip/hip_runtime.h>

#define N_EDGE 262144
#define N_TRI  1048576
#define DIM    128
#define NRBF   6
#define ADIM   49
#define NBIL   8
#define TE     32
#define LDA    136   // sAb row stride in ushorts (272 B) — bank-spread padding

typedef __attribute__((ext_vector_type(8))) short bf16x8;
typedef __attribute__((ext_vector_type(4))) float f32x4;

__device__ __forceinline__ float silu_f(float x) { return x / (1.f + __expf(-x)); }
__device__ __forceinline__ unsigned short f2bf(float f) {
    unsigned int u = __float_as_uint(f);
    return (unsigned short)((u + 0x7FFFu + ((u >> 16) & 1u)) >> 16);
}

// ---------------------------------------------------------------------------
// prep: 9 DxD weights -> bf16 transposed [n][k]; final_w -> bf16 direct cast
// slots: 0=nbr_m_w 1=m_ji_w 2=post_w 3..8=res_w(6) then fwb [128][1024]
// ---------------------------------------------------------------------------
__global__ __launch_bounds__(256) void prep_w_k(
    const float* __restrict__ nbr, const float* __restrict__ mji,
    const float* __restrict__ post, const float* __restrict__ res,
    const float* __restrict__ fw, unsigned short* __restrict__ wt)
{
    int idx = blockIdx.x * 256 + threadIdx.x;          // 278528 total
    if (idx < 9 * 16384) {
        int m = idx >> 14, rr = idx & 16383;
        int n = rr >> 7, k = rr & 127;
        const float* src = (m == 0) ? nbr : (m == 1) ? mji : (m == 2) ? post
                          : (res + (size_t)(m - 3) * 16384);
        wt[idx] = f2bf(src[k * DIM + n]);
    } else {
        wt[idx] = f2bf(fw[idx - 9 * 16384]);           // [i][j*128+l] == [n][k]
    }
}

// ---------------------------------------------------------------------------
// triplet stage: t_a = a_sbf @ a_sbf_w  [W,8]; atomic segment-sum into ta_sum
// ---------------------------------------------------------------------------
__global__ __launch_bounds__(256) void triplet_ta_k(
    const float* __restrict__ a_sbf, const float* __restrict__ a_sbf_w,
    const int* __restrict__ kj_idx, float* __restrict__ ta_sum)
{
    __shared__ __align__(16) float sA[256 * ADIM];
    __shared__ float sWa[ADIM * NBIL];
    const int tid = threadIdx.x;
    const size_t w0 = (size_t)blockIdx.x * 256;

    {
        const float4* src = (const float4*)(a_sbf + w0 * ADIM);
        float4* dst = (float4*)sA;
        const int n4 = (256 * ADIM) / 4;
        for (int i = tid; i < n4; i += 256) dst[i] = src[i];
    }
    for (int i = tid; i < ADIM * NBIL; i += 256) sWa[i] = a_sbf_w[i];
    __syncthreads();

    float ta[NBIL];
    #pragma unroll
    for (int j = 0; j < NBIL; ++j) ta[j] = 0.0f;
    const float* row = sA + tid * ADIM;
    #pragma unroll
    for (int k = 0; k < ADIM; ++k) {
        float v = row[k];
        #pragma unroll
        for (int j = 0; j < NBIL; ++j) ta[j] = fmaf(v, sWa[k * NBIL + j], ta[j]);
    }
    const int e = kj_idx[w0 + tid];
    float* dst = ta_sum + (size_t)e * NBIL;
    #pragma unroll
    for (int j = 0; j < NBIL; ++j) atomicAdd(dst + j, ta[j]);
}

// ---------------------------------------------------------------------------
// fused edge kernel, MFMA version. 4 waves; wave w owns rows 0..31 x cols
// [w*32, w*32+32). Fragment ownership identical across stages -> transf and
// x stay in registers; activations round-trip LDS only as bf16 A-operands.
// ---------------------------------------------------------------------------
__global__ __launch_bounds__(256) void edge_main_k(
    const float* __restrict__ m_ji, const float* __restrict__ e_rbf,
    const float* __restrict__ ta_sum, const unsigned short* __restrict__ wt,
    const float* __restrict__ nbr_m_b, const float* __restrict__ e_rbf_w,
    const float* __restrict__ m_ji_b, const float* __restrict__ post_b,
    const float* __restrict__ res_b, float* __restrict__ out)
{
    __shared__ __align__(16) unsigned short sAb[TE * LDA];
    __shared__ float sTA[TE * NBIL];
    __shared__ float sE[TE * NRBF];
    __shared__ float sEw[NRBF * DIM];

    const int tid  = threadIdx.x;
    const int lane = tid & 63;
    const int ml   = lane & 15;
    const int g    = lane >> 4;
    const int n0   = (tid >> 6) * 32;
    const size_t e0 = (size_t)blockIdx.x * TE;

    // stage m_ji tile -> sAb (bf16)
    #pragma unroll
    for (int i = 0; i < 2; ++i) {
        int cid = tid + i * 256;                      // 512 16B-chunks
        int row = cid >> 4, c = cid & 15;
        const float* src = m_ji + (e0 + row) * DIM + c * 8;
        float4 v0 = *(const float4*)(src);
        float4 v1 = *(const float4*)(src + 4);
        bf16x8 hv;
        hv[0] = (short)f2bf(v0.x); hv[1] = (short)f2bf(v0.y);
        hv[2] = (short)f2bf(v0.z); hv[3] = (short)f2bf(v0.w);
        hv[4] = (short)f2bf(v1.x); hv[5] = (short)f2bf(v1.y);
        hv[6] = (short)f2bf(v1.z); hv[7] = (short)f2bf(v1.w);
        *(bf16x8*)(sAb + row * LDA + c * 8) = hv;
    }
    sTA[tid] = ta_sum[e0 * NBIL + tid];
    if (tid < TE * NRBF) sE[tid] = e_rbf[e0 * NRBF + tid];
    for (int i = tid; i < NRBF * DIM; i += 256) sEw[i] = e_rbf_w[i];
    __syncthreads();

    bf16x8 A[2][4];
    f32x4 acc[2][2], tr[2][2], xr[2][2];

    auto load_a = [&]() {
        #pragma unroll
        for (int mt = 0; mt < 2; ++mt) {
            const unsigned short* rb = sAb + (mt * 16 + ml) * LDA + g * 8;
            #pragma unroll
            for (int ks = 0; ks < 4; ++ks)
                A[mt][ks] = *(const bf16x8*)(rb + ks * 32);
        }
    };
    auto mfma_b = [&](const unsigned short* wtm, int ldk, int kbase) {
        #pragma unroll
        for (int nt = 0; nt < 2; ++nt) {
            const unsigned short* wb =
                wtm + (size_t)(n0 + nt * 16 + ml) * ldk + kbase + g * 8;
            #pragma unroll
            for (int ks = 0; ks < 4; ++ks) {
                bf16x8 b = *(const bf16x8*)(wb + ks * 32);
                acc[0][nt] = __builtin_amdgcn_mfma_f32_16x16x32_bf16(A[0][ks], b, acc[0][nt], 0, 0, 0);
                acc[1][nt] = __builtin_amdgcn_mfma_f32_16x16x32_bf16(A[1][ks], b, acc[1][nt], 0, 0, 0);
            }
        }
    };
    auto init_bias = [&](const float* bp) {
        #pragma unroll
        for (int nt = 0; nt < 2; ++nt) {
            float bv = bp[n0 + nt * 16 + ml];
            #pragma unroll
            for (int r = 0; r < 4; ++r) { acc[0][nt][r] = bv; acc[1][nt][r] = bv; }
        }
    };
    auto store_acc = [&]() {      // acc -> sAb bf16 (guarded both sides)
        __syncthreads();
        #pragma unroll
        for (int mt = 0; mt < 2; ++mt)
        #pragma unroll
        for (int r = 0; r < 4; ++r) {
            int row = mt * 16 + g * 4 + r;
            #pragma unroll
            for (int nt = 0; nt < 2; ++nt)
                sAb[row * LDA + n0 + nt * 16 + ml] = f2bf(acc[mt][nt][r]);
        }
        __syncthreads();
    };

    // ---- transf = silu(m_ji @ m_ji_w + b)  (kept in regs)
    load_a();
    init_bias(m_ji_b);
    mfma_b(wt + 1 * 16384, DIM, 0);
    #pragma unroll
    for (int mt = 0; mt < 2; ++mt)
    #pragma unroll
    for (int nt = 0; nt < 2; ++nt)
    #pragma unroll
    for (int r = 0; r < 4; ++r) tr[mt][nt][r] = silu_f(acc[mt][nt][r]);

    // ---- me = silu(m_ji @ nbr_m_w + b) * (e_rbf @ e_rbf_w)   (A still m_ji)
    init_bias(nbr_m_b);
    mfma_b(wt + 0, DIM, 0);
    {
        float ewc[2][NRBF];
        #pragma unroll
        for (int nt = 0; nt < 2; ++nt)
        #pragma unroll
        for (int q = 0; q < NRBF; ++q) ewc[nt][q] = sEw[q * DIM + n0 + nt * 16 + ml];
        #pragma unroll
        for (int mt = 0; mt < 2; ++mt)
        #pragma unroll
        for (int r = 0; r < 4; ++r) {
            int row = mt * 16 + g * 4 + r;
            float er[NRBF];
            #pragma unroll
            for (int q = 0; q < NRBF; ++q) er[q] = sE[row * NRBF + q];
            #pragma unroll
            for (int nt = 0; nt < 2; ++nt) {
                float te = 0.f;
                #pragma unroll
                for (int q = 0; q < NRBF; ++q) te = fmaf(er[q], ewc[nt][q], te);
                acc[mt][nt][r] = silu_f(acc[mt][nt][r]) * te;
            }
        }
    }
    store_acc();                                   // sAb = me

    // ---- bilinear: dir = sum_j ta[:,j] * (me @ fw_j^T); A-frags loaded once
    load_a();
    f32x4 dir[2][2];
    #pragma unroll
    for (int mt = 0; mt < 2; ++mt)
    #pragma unroll
    for (int nt = 0; nt < 2; ++nt)
    #pragma unroll
    for (int r = 0; r < 4; ++r) dir[mt][nt][r] = 0.f;
    const unsigned short* fwb = wt + 9 * 16384;
    for (int j = 0; j < NBIL; ++j) {
        #pragma unroll
        for (int mt = 0; mt < 2; ++mt)
        #pragma unroll
        for (int nt = 0; nt < 2; ++nt)
        #pragma unroll
        for (int r = 0; r < 4; ++r) acc[mt][nt][r] = 0.f;
        mfma_b(fwb, NBIL * DIM, j * DIM);
        #pragma unroll
        for (int mt = 0; mt < 2; ++mt) {
            float tv[4];
            #pragma unroll
            for (int r = 0; r < 4; ++r) tv[r] = sTA[(mt * 16 + g * 4 + r) * NBIL + j];
            #pragma unroll
            for (int nt = 0; nt < 2; ++nt)
            #pragma unroll
            for (int r = 0; r < 4; ++r)
                dir[mt][nt][r] = fmaf(tv[r], acc[mt][nt][r], dir[mt][nt][r]);
        }
    }
    #pragma unroll
    for (int mt = 0; mt < 2; ++mt)
    #pragma unroll
    for (int nt = 0; nt < 2; ++nt)
    #pragma unroll
    for (int r = 0; r < 4; ++r) {
        xr[mt][nt][r] = dir[mt][nt][r] + tr[mt][nt][r];
        acc[mt][nt][r] = xr[mt][nt][r];
    }
    store_acc();                                   // sAb = bf16(x)

    auto res_block = [&](const unsigned short* wa, const float* ba,
                         const unsigned short* wbm, const float* bb) {
        load_a();
        init_bias(ba);
        mfma_b(wa, DIM, 0);
        #pragma unroll
        for (int mt = 0; mt < 2; ++mt)
        #pragma unroll
        for (int nt = 0; nt < 2; ++nt)
        #pragma unroll
        for (int r = 0; r < 4; ++r) acc[mt][nt][r] = silu_f(acc[mt][nt][r]);
        store_acc();                               // sAb = h
        load_a();
        init_bias(bb);
        mfma_b(wbm, DIM, 0);
        #pragma unroll
        for (int mt = 0; mt < 2; ++mt)
        #pragma unroll
        for (int nt = 0; nt < 2; ++nt)
        #pragma unroll
        for (int r = 0; r < 4; ++r) {
            xr[mt][nt][r] += silu_f(acc[mt][nt][r]);
            acc[mt][nt][r] = xr[mt][nt][r];
        }
        store_acc();                               // sAb = bf16(x)
    };

    res_block(wt + 3 * 16384, res_b + 0, wt + 4 * 16384, res_b + 128);

    // ---- post: x = silu(x @ post_w + b) + transf
    load_a();
    init_bias(post_b);
    mfma_b(wt + 2 * 16384, DIM, 0);
    #pragma unroll
    for (int mt = 0; mt < 2; ++mt)
    #pragma unroll
    for (int nt = 0; nt < 2; ++nt)
    #pragma unroll
    for (int r = 0; r < 4; ++r) {
        xr[mt][nt][r] = silu_f(acc[mt][nt][r]) + tr[mt][nt][r];
        acc[mt][nt][r] = xr[mt][nt][r];
    }
    store_acc();

    res_block(wt + 5 * 16384, res_b + 256, wt + 6 * 16384, res_b + 384);

    // ---- res2, second half fused with global store
    load_a();
    init_bias(res_b + 512);
    mfma_b(wt + 7 * 16384, DIM, 0);
    #pragma unroll
    for (int mt = 0; mt < 2; ++mt)
    #pragma unroll
    for (int nt = 0; nt < 2; ++nt)
    #pragma unroll
    for (int r = 0; r < 4; ++r) acc[mt][nt][r] = silu_f(acc[mt][nt][r]);
    store_acc();
    load_a();
    init_bias(res_b + 640);
    mfma_b(wt + 8 * 16384, DIM, 0);
    #pragma unroll
    for (int mt = 0; mt < 2; ++mt)
    #pragma unroll
    for (int r = 0; r < 4; ++r) {
        int row = mt * 16 + g * 4 + r;
        #pragma unroll
        for (int nt = 0; nt < 2; ++nt)
            out[(e0 + row) * DIM + n0 + nt * 16 + ml] =
                silu_f(acc[mt][nt][r]) + xr[mt][nt][r];
    }
}

// ---------------------------------------------------------------------------
extern "C" void kernel_launch(void* const* d_in, const int* in_sizes, int n_in,
                              void* d_out, int out_size, void* d_ws, size_t ws_size,
                              hipStream_t stream)
{
    (void)in_sizes; (void)n_in; (void)out_size; (void)ws_size;
    const float* m_ji    = (const float*)d_in[0];
    const float* e_rbf   = (const float*)d_in[1];
    const float* a_sbf   = (const float*)d_in[2];
    const int*   kj_idx  = (const int*)d_in[5];
    const float* nbr_m_w = (const float*)d_in[6];
    const float* nbr_m_b = (const float*)d_in[7];
    const float* e_rbf_w = (const float*)d_in[8];
    const float* a_sbf_w = (const float*)d_in[9];
    const float* final_w = (const float*)d_in[10];
    const float* m_ji_w  = (const float*)d_in[11];
    const float* m_ji_b  = (const float*)d_in[12];
    const float* post_w  = (const float*)d_in[13];
    const float* post_b  = (const float*)d_in[14];
    const float* res_w   = (const float*)d_in[15];
    const float* res_b   = (const float*)d_in[16];
    float* out = (float*)d_out;

    float* ta = (float*)d_ws;                                    // [E,8] f32
    unsigned short* wt =
        (unsigned short*)((char*)d_ws + (size_t)N_EDGE * NBIL * sizeof(float));

    hipMemsetAsync(ta, 0, (size_t)N_EDGE * NBIL * sizeof(float), stream);
    prep_w_k<<<1088, 256, 0, stream>>>(nbr_m_w, m_ji_w, post_w, res_w, final_w, wt);
    triplet_ta_k<<<N_TRI / 256, 256, 0, stream>>>(a_sbf, a_sbf_w, kj_idx, ta);
    edge_main_k<<<N_EDGE / TE, 256, 0, stream>>>(m_ji, e_rbf, ta, wt,
        nbr_m_b, e_rbf_w, m_ji_b, post_b, res_b, out);
}